// Round 6
// baseline (305.544 us; speedup 1.0000x reference)
//
#include <hip/hip_runtime.h>
#include <math.h>

typedef __bf16 bf16x8 __attribute__((ext_vector_type(8)));
typedef float f32x4 __attribute__((ext_vector_type(4)));
typedef unsigned short us8 __attribute__((ext_vector_type(8)));

#define B_ 2
#define L_ 2048
#define D_ 2048
#define H_ 16
#define DH 128

__device__ __forceinline__ unsigned short f2b(float f) {
  union { float f; unsigned u; } v; v.f = f;
  unsigned u = v.u;
  return (unsigned short)((u + 0x7fffu + ((u >> 16) & 1u)) >> 16);
}
__device__ __forceinline__ float b2f(unsigned short h) {
  union { unsigned u; float f; } v; v.u = ((unsigned)h) << 16;
  return v.f;
}

#define GLD16(g, l) __builtin_amdgcn_global_load_lds(                          \
    (const __attribute__((address_space(1))) void*)(g),                        \
    (__attribute__((address_space(3))) void*)(l), 16, 0, 0)

// ---------------- fp32 -> bf16 convert ----------------
__global__ void f32_to_bf16(const float* __restrict__ in,
                            unsigned short* __restrict__ out, int n4) {
  int i = blockIdx.x * blockDim.x + threadIdx.x;
  const int stride = gridDim.x * blockDim.x;
  for (; i < n4; i += stride) {
    const float4 v = ((const float4*)in)[i];
    ushort4 o;
    o.x = f2b(v.x); o.y = f2b(v.y); o.z = f2b(v.z); o.w = f2b(v.w);
    ((ushort4*)out)[i] = o;
  }
}

// ---------------- 8-phase 256x256x64 GEMM: C[m,n] = sum_k A[m,k]*B[n,k] ----------------
// m201 template: raw s_barrier (NO sched_barrier order-pinning), explicit
// lgkmcnt(0) after the pre-MFMA barrier, counted vmcnt drains (>=3-phase-old
// loads only), T2 swizzle (conflicts=0 verified), T5 setprio, T1 XCD swizzle.

#define SBAR() __builtin_amdgcn_s_barrier()
#define LGK0() asm volatile("s_waitcnt lgkmcnt(0)")
#define LGK8() asm volatile("s_waitcnt lgkmcnt(8)")
#define VMC4() asm volatile("s_waitcnt vmcnt(4)" ::: "memory")
#define VMC0() asm volatile("s_waitcnt vmcnt(0)" ::: "memory")

#define LOAD_A(BUF, MH)                                                        \
  _Pragma("unroll") for (int q = 0; q < 4; ++q) {                              \
    const int rowA = (MH) * 64 + q * 16 + lo;                                  \
    _Pragma("unroll") for (int kk = 0; kk < 2; ++kk)                           \
        af[q][kk] = *(const bf16x8*)&lds[0][BUF][wmh]                          \
            [rowA * 64 + ((kk * 4 + hi) ^ sw) * 8];                            \
  }

#define LOAD_B(BUF, NH)                                                        \
  _Pragma("unroll") for (int j = 0; j < 2; ++j) {                              \
    const int rowB = bro + ((NH) * 2 + j) * 16;                                \
    _Pragma("unroll") for (int kk = 0; kk < 2; ++kk)                           \
        bfr[NH][j][kk] = *(const bf16x8*)&lds[1][BUF][bhalf]                   \
            [rowB * 64 + ((kk * 4 + hi) ^ sw) * 8];                            \
  }

#define MFMA16(MH, NH)                                                         \
  do {                                                                         \
    __builtin_amdgcn_s_setprio(1);                                             \
    _Pragma("unroll") for (int q = 0; q < 4; ++q) {                            \
      _Pragma("unroll") for (int j = 0; j < 2; ++j) {                          \
        acc[(MH) * 4 + q][(NH) * 2 + j] =                                      \
            __builtin_amdgcn_mfma_f32_16x16x32_bf16(                           \
                af[q][0], bfr[NH][j][0], acc[(MH) * 4 + q][(NH) * 2 + j],      \
                0, 0, 0);                                                      \
        acc[(MH) * 4 + q][(NH) * 2 + j] =                                      \
            __builtin_amdgcn_mfma_f32_16x16x32_bf16(                           \
                af[q][1], bfr[NH][j][1], acc[(MH) * 4 + q][(NH) * 2 + j],      \
                0, 0, 0);                                                      \
      }                                                                        \
    }                                                                          \
    __builtin_amdgcn_s_setprio(0);                                             \
  } while (0)

template <bool OUT_BF16>
__global__ __launch_bounds__(512)
void gemm8p(const unsigned short* __restrict__ A,
            const unsigned short* __restrict__ Bm,
            void* __restrict__ Cv, int M, int N, int K) {
  __shared__ __align__(16) unsigned short lds[2][2][2][128 * 64];
  const int tid = threadIdx.x;
  const int w = tid >> 6, lane = tid & 63;
  const int lo = lane & 15, hi = lane >> 4, sw = lo & 7;
  const int wmh = w >> 2;        // this wave's A half (rows wmh*128..+127)
  const int wn = (w & 3) * 64;   // this wave's 64-col C window
  const int bhalf = wn >> 7, bro = (wn & 64) + lo;
  const int GM = M >> 8;
  const int nwg = gridDim.x;
  const int f = blockIdx.x;
  const int v = (f & 7) * (nwg >> 3) + (f >> 3);  // bijective XCD swizzle
  const int bn = v / GM, bm = v % GM;             // bn-major chunks per XCD
  const int NI = K >> 7;

  auto stageU = [&](int mat, int buf, int half, int tile) {
    const unsigned short* G = mat ? Bm : A;
    const int r256 = (mat ? bn : bm) * 256 + half * 128;
#pragma unroll
    for (int u = 0; u < 2; ++u) {
      const int c = u * 512 + tid;
      const int row = c >> 3;
      const int gs = (c & 7) ^ (row & 7);  // pre-swizzled source slot
      GLD16(G + (long)(r256 + row) * K + tile * 64 + gs * 8,
            &lds[mat][buf][half][(u * 512 + (tid & ~63)) * 8]);
    }
  };

  f32x4 acc[8][4] = {};
  bf16x8 af[4][2], bfr[2][2][2];

  // prologue: tile0 full -> buf0 (4 units), tile1.A -> buf1 (2 units)
  stageU(0, 0, 0, 0); stageU(0, 0, 1, 0);
  stageU(1, 0, 0, 0); stageU(1, 0, 1, 0);
  stageU(0, 1, 0, 1); stageU(0, 1, 1, 1);
  VMC4();  // tile0's 4 units landed; buf1.A pair may fly
  SBAR();

  for (int i = 0; i < NI; ++i) {
    const int tOdd = 2 * i + 1;
    const bool nx = (i + 1 < NI);
    // p1: buf0 quad (0,0); stage buf1.B (tile 2i+1)
    LOAD_A(0, 0) LOAD_B(0, 0)
    stageU(1, 1, 0, tOdd); stageU(1, 1, 1, tOdd);
    LGK8();
    SBAR(); LGK0(); MFMA16(0, 0); SBAR();
    // p2: quad (0,1)
    LOAD_B(0, 1)
    SBAR(); LGK0(); MFMA16(0, 1); SBAR();
    // p3: quad (1,1)
    LOAD_A(0, 1)
    SBAR(); LGK0(); MFMA16(1, 1); SBAR();
    // p4: quad (1,0) [no reads]; stage buf0.A (tile 2i+2); drain 3-phase-old
    if (nx) { stageU(0, 0, 0, tOdd + 1); stageU(0, 0, 1, tOdd + 1); }
    SBAR(); MFMA16(1, 0);
    if (nx) VMC4(); else VMC0();  // buf1.A (p8 prev) + buf1.B (p1) landed
    SBAR();
    // p5: buf1 quad (0,0); stage buf0.B (tile 2i+2)
    LOAD_A(1, 0) LOAD_B(1, 0)
    if (nx) { stageU(1, 0, 0, tOdd + 1); stageU(1, 0, 1, tOdd + 1); }
    LGK8();
    SBAR(); LGK0(); MFMA16(0, 0); SBAR();
    // p6: quad (0,1)
    LOAD_B(1, 1)
    SBAR(); LGK0(); MFMA16(0, 1); SBAR();
    // p7: quad (1,1)
    LOAD_A(1, 1)
    SBAR(); LGK0(); MFMA16(1, 1); SBAR();
    // p8: quad (1,0) [no reads]; stage buf1.A (tile 2i+3); drain
    if (nx) { stageU(0, 1, 0, tOdd + 2); stageU(0, 1, 1, tOdd + 2); }
    SBAR(); MFMA16(1, 0);
    if (nx) VMC4(); else VMC0();  // buf0.A (p4) + buf0.B (p5) landed
    SBAR();
  }

  const int r0 = bm * 256 + wmh * 128;
  const int c0 = bn * 256 + wn;
#pragma unroll
  for (int mi = 0; mi < 8; ++mi) {
#pragma unroll
    for (int r = 0; r < 4; ++r) {
      const long row = r0 + mi * 16 + hi * 4 + r;
#pragma unroll
      for (int ni = 0; ni < 4; ++ni) {
        const int col = c0 + ni * 16 + lo;
        if (OUT_BF16)
          ((unsigned short*)Cv)[row * N + col] = f2b(acc[mi][ni][r]);
        else
          ((float*)Cv)[row * N + col] = acc[mi][ni][r];
      }
    }
  }
}

// ---------------- RoPE + scatter to [B,H,L,dh]; Q scaled by log2(e)/sqrt(dh) ----------------
__global__ void rope_qk(const unsigned short* __restrict__ qkv,
                        unsigned short* __restrict__ Qo,
                        unsigned short* __restrict__ Ko) {
  const int idx = blockIdx.x * 256 + threadIdx.x;
  const int i = idx & 63;
  const int l = (idx >> 6) & (L_ - 1);
  const int h = (idx >> 17) & (H_ - 1);
  const int b = idx >> 21;
  const float invf = exp2f(-(float)i * 0.20762050593045077f);
  const float ang = (float)l * invf;
  float sn, cs;
  sincosf(ang, &sn, &cs);
  const long base = ((long)b * L_ + l) * (3 * D_) + h * DH + 2 * i;
  const unsigned qin = *(const unsigned*)&qkv[base];
  const unsigned kin = *(const unsigned*)&qkv[base + D_];
  const float q0 = b2f((unsigned short)qin), q1 = b2f((unsigned short)(qin >> 16));
  const float k0 = b2f((unsigned short)kin), k1 = b2f((unsigned short)(kin >> 16));
  const float sc = 0.12751743f;  // log2(e)/sqrt(128): softmax in exp2 domain
  const float qo0 = (q0 * cs - q1 * sn) * sc, qo1 = (q1 * cs + q0 * sn) * sc;
  const float ko0 = (k0 * cs - k1 * sn), ko1 = (k1 * cs + k0 * sn);
  const long oo = ((long)(b * H_ + h) * L_ + l) * DH + 2 * i;
  *(unsigned*)&Qo[oo] = (unsigned)f2b(qo0) | ((unsigned)f2b(qo1) << 16);
  *(unsigned*)&Ko[oo] = (unsigned)f2b(ko0) | ((unsigned)f2b(ko1) << 16);
}

// ---------------- V pack into MFMA B-fragment tiles ----------------
__global__ __launch_bounds__(256)
void v_fragpack(const unsigned short* __restrict__ qkv,
                unsigned short* __restrict__ Vf) {
  const int lblk = blockIdx.x;  // L/64
  const int bh = blockIdx.y;    // B*H
  const int b = bh >> 4, h = bh & 15;
  __shared__ unsigned short tile[64 * 137];
  const int tid = threadIdx.x;
  const int l0 = lblk * 64;
#pragma unroll
  for (int j = 0; j < 4; ++j) {
    const int c = j * 256 + tid;
    const int row = c >> 4, col8 = c & 15;
    const us8 v = *(const us8*)&qkv[((long)b * L_ + l0 + row) * (3 * D_) +
                                    2 * D_ + h * DH + col8 * 8];
    unsigned short* dst = &tile[row * 137 + col8 * 8];
#pragma unroll
    for (int e = 0; e < 8; ++e) dst[e] = v[e];
  }
  __syncthreads();
#pragma unroll
  for (int j = 0; j < 4; ++j) {
    const int c = j * 256 + tid;
    const int k32l = c >> 9, t2 = (c >> 6) & 7, lane = c & 63;
    const int lo = lane & 15, hi = lane >> 4;
    us8 v;
#pragma unroll
    for (int e = 0; e < 8; ++e)
      v[e] = tile[(k32l * 32 + hi * 8 + e) * 137 + t2 * 16 + lo];
    *(us8*)&Vf[(((size_t)bh * 64 + lblk * 2 + k32l) * 8 + t2) * 512 + lane * 8] = v;
  }
}

// ---------------- causal flash attention: fold-paired q-tiles, swapped QK^T ----------------
__global__ __launch_bounds__(256, 2)
void flash_attn3(const unsigned short* __restrict__ Q,
                 const unsigned short* __restrict__ Kg,
                 const unsigned short* __restrict__ Vf,
                 unsigned short* __restrict__ Y) {
  const int p = blockIdx.x;  // 0..15
  const int tA = p, tB = (L_ / 64 - 1) - p;
  const int h = blockIdx.y, b = blockIdx.z;
  const int tid = threadIdx.x;
  const int wave = tid >> 6, lane = tid & 63;
  const int lo = lane & 15, hi = lane >> 4;
  const int swz = (lo & 7) << 4;
  const int qA = tA * 64 + wave * 16;
  const int qB = tB * 64 + wave * 16;
  const long hoff = ((long)(b * H_ + h)) * L_ * DH;
  const unsigned short* Qh = Q + hoff;
  const unsigned short* Kh = Kg + hoff;
  const unsigned short* Vfh = Vf + ((size_t)(b * H_ + h)) * (64 * 8 * 512);

  __shared__ unsigned short lK[2][64 * 128];
  __shared__ unsigned short pl[4][2][16 * 72];
  unsigned short* plA = &pl[wave][0][0];
  unsigned short* plB = &pl[wave][1][0];

  auto stage = [&](int bufi, int kv0s) {
    unsigned short* bk = &lK[bufi][0];
#pragma unroll
    for (int j = 0; j < 4; ++j) {
      const int c = j * 256 + tid;
      const int row = c >> 4;
      const int soff = ((c & 15) ^ (row & 7)) << 3;
      GLD16(Kh + (long)(kv0s + row) * DH + soff, &bk[(c & ~63) * 8]);
    }
  };

  bf16x8 qfA[4], qfB[4];
#pragma unroll
  for (int s = 0; s < 4; ++s) {
    qfA[s] = *(const bf16x8*)&Qh[(long)(qA + lo) * DH + s * 32 + hi * 8];
    qfB[s] = *(const bf16x8*)&Qh[(long)(qB + lo) * DH + s * 32 + hi * 8];
  }

  float mA = -INFINITY, lsA = 0.f, mB = -INFINITY, lsB = 0.f;
  f32x4 yA[8] = {}, yB[8] = {};

  auto softmax = [&](f32x4 (&st)[4], float& m, float& lsum, f32x4 (&yacc)[8],
                     unsigned short* plw, int qw, int kv0) {
    if (kv0 + 63 > qw) {
      const int d0 = qw + lo - kv0 - hi * 4;
#pragma unroll
      for (int t = 0; t < 4; ++t) {
        const int dt = d0 - t * 16;
#pragma unroll
        for (int r = 0; r < 4; ++r)
          if (r > dt) st[t][r] = -INFINITY;
      }
    }
    float tm0 = fmaxf(fmaxf(st[0][0], st[0][1]), fmaxf(st[0][2], st[0][3]));
    float tm1 = fmaxf(fmaxf(st[1][0], st[1][1]), fmaxf(st[1][2], st[1][3]));
    float tm2 = fmaxf(fmaxf(st[2][0], st[2][1]), fmaxf(st[2][2], st[2][3]));
    float tm3 = fmaxf(fmaxf(st[3][0], st[3][1]), fmaxf(st[3][2], st[3][3]));
    float rm = fmaxf(fmaxf(tm0, tm1), fmaxf(tm2, tm3));
    rm = fmaxf(rm, __shfl_xor(rm, 16));
    rm = fmaxf(rm, __shfl_xor(rm, 32));
    if (!__all(rm <= m + 8.f)) {
      const float mn = fmaxf(m, rm);
      const float alpha = exp2f(m - mn);
      m = mn;
      lsum *= alpha;
      float ar[4];
#pragma unroll
      for (int r = 0; r < 4; ++r) ar[r] = __shfl(alpha, hi * 4 + r);
#pragma unroll
      for (int t2 = 0; t2 < 8; ++t2)
#pragma unroll
        for (int r = 0; r < 4; ++r) yacc[t2][r] *= ar[r];
    }
    float rs = 0.f;
#pragma unroll
    for (int t = 0; t < 4; ++t) {
#pragma unroll
      for (int r2 = 0; r2 < 2; ++r2) {
        const float e0 = exp2f(st[t][2 * r2] - m);
        const float e1 = exp2f(st[t][2 * r2 + 1] - m);
        rs += e0 + e1;
        const unsigned short u0 = __builtin_bit_cast(unsigned short, (__bf16)e0);
        const unsigned short u1 = __builtin_bit_cast(unsigned short, (__bf16)e1);
        *(unsigned*)&plw[lo * 72 + t * 16 + hi * 4 + 2 * r2] =
            (unsigned)u0 | ((unsigned)u1 << 16);
      }
    }
    rs += __shfl_xor(rs, 16);
    rs += __shfl_xor(rs, 32);
    lsum += rs;
  };

  const int nIter = tB + 1;
  stage(0, 0);
  __syncthreads();

  for (int it = 0; it < nIter; ++it) {
    const int kv0 = it * 64;
    const bool aAct = (it <= tA);
    if (it + 1 < nIter) stage((it + 1) & 1, kv0 + 64);
    const char* bkc = (const char*)&lK[it & 1][0];
    f32x4 stA[4] = {}, stB[4] = {};
    if (aAct) {
#pragma unroll
      for (int s = 0; s < 4; ++s) {
        const int inner = (lo * 256 + s * 64 + hi * 16) ^ swz;
#pragma unroll
        for (int t = 0; t < 4; ++t) {
          const bf16x8 kf = *(const bf16x8*)(bkc + t * 4096 + inner);
          stA[t] = __builtin_amdgcn_mfma_f32_16x16x32_bf16(kf, qfA[s], stA[t], 0, 0, 0);
          stB[t] = __builtin_amdgcn_mfma_f32_16x16x32_bf16(kf, qfB[s], stB[t], 0, 0, 0);
        }
      }
    } else {
#pragma unroll
      for (int s = 0; s < 4; ++s) {
        const int inner = (lo * 256 + s * 64 + hi * 16) ^ swz;
#pragma unroll
        for (int t = 0; t < 4; ++t) {
          const bf16x8 kf = *(const bf16x8*)(bkc + t * 4096 + inner);
          stB[t] = __builtin_amdgcn_mfma_f32_16x16x32_bf16(kf, qfB[s], stB[t], 0, 0, 0);
        }
      }
    }
    if (aAct) softmax(stA, mA, lsA, yA, plA, qA, kv0);
    softmax(stB, mB, lsB, yB, plB, qB, kv0);
    const unsigned short* vbase = Vfh + (size_t)(it * 16) * 512 + lane * 8;
#pragma unroll
    for (int kt = 0; kt < 2; ++kt) {
      bf16x8 vf[8];
#pragma unroll
      for (int t2 = 0; t2 < 8; ++t2)
        vf[t2] = *(const bf16x8*)(vbase + (size_t)(kt * 8 + t2) * 512);
      const bf16x8 pfB = *(const bf16x8*)&plB[lo * 72 + kt * 32 + hi * 8];
#pragma unroll
      for (int t2 = 0; t2 < 8; ++t2)
        yB[t2] = __builtin_amdgcn_mfma_f32_16x16x32_bf16(pfB, vf[t2], yB[t2], 0, 0, 0);
      if (aAct) {
        const bf16x8 pfA = *(const bf16x8*)&plA[lo * 72 + kt * 32 + hi * 8];
#pragma unroll
        for (int t2 = 0; t2 < 8; ++t2)
          yA[t2] = __builtin_amdgcn_mfma_f32_16x16x32_bf16(pfA, vf[t2], yA[t2], 0, 0, 0);
      }
    }
    __syncthreads();
  }

  auto wout = [&](f32x4 (&yacc)[8], float lsum, int qw) {
    const float inv = 1.f / lsum;
    float ir[4];
#pragma unroll
    for (int r = 0; r < 4; ++r) ir[r] = __shfl(inv, hi * 4 + r);
#pragma unroll
    for (int r = 0; r < 4; ++r) {
      const long row = qw + hi * 4 + r;
      unsigned short* yrow = Y + ((long)b * L_ + row) * D_ + h * DH;
#pragma unroll
      for (int t2 = 0; t2 < 8; ++t2)
        yrow[t2 * 16 + lo] = f2b(yacc[t2][r] * ir[r]);
    }
  };
  wout(yA, lsA, qA);
  wout(yB, lsB, qB);
}

extern "C" void kernel_launch(void* const* d_in, const int* in_sizes, int n_in,
                              void* d_out, int out_size, void* d_ws, size_t ws_size,
                              hipStream_t stream) {
  const float* x = (const float*)d_in[0];
  const float* wqkv = (const float*)d_in[1];
  const float* wo = (const float*)d_in[2];
  float* out = (float*)d_out;

  unsigned short* ws = (unsigned short*)d_ws;
  const size_t N_X = (size_t)B_ * L_ * D_;
  const size_t N_WQKV = (size_t)3 * D_ * D_;
  const size_t N_WO = (size_t)D_ * D_;
  const size_t N_QKV = (size_t)B_ * L_ * 3 * D_;
  const size_t N_HEAD = (size_t)B_ * H_ * L_ * DH;
  unsigned short* xb = ws;
  unsigned short* wqkb = xb + N_X;
  unsigned short* wob = wqkb + N_WQKV;
  unsigned short* qkv = wob + N_WO;
  unsigned short* Qb = qkv + N_QKV;
  unsigned short* Kb = Qb + N_HEAD;
  unsigned short* Vf = Kb + N_HEAD;
  unsigned short* Yb = Vf + N_HEAD;
  const size_t need = (size_t)(Yb + N_HEAD - ws) * sizeof(unsigned short);
  if (ws_size < need) return;

  f32_to_bf16<<<2048, 256, 0, stream>>>(x, xb, (int)(N_X / 4));
  f32_to_bf16<<<2048, 256, 0, stream>>>(wqkv, wqkb, (int)(N_WQKV / 4));
  f32_to_bf16<<<2048, 256, 0, stream>>>(wo, wob, (int)(N_WO / 4));

  // qkv = x @ W_qkv^T : M=4096, N=6144, K=2048 -> 384 blocks
  gemm8p<true><<<(B_ * L_ / 256) * (3 * D_ / 256), 512, 0, stream>>>(
      xb, wqkb, qkv, B_ * L_, 3 * D_, D_);

  rope_qk<<<(B_ * H_ * L_ * 64) / 256, 256, 0, stream>>>(qkv, Qb, Kb);
  v_fragpack<<<dim3(L_ / 64, B_ * H_), 256, 0, stream>>>(qkv, Vf);

  flash_attn3<<<dim3(16, H_, B_), 256, 0, stream>>>(Qb, Kb, Vf, Yb);

  // out = y @ W_o^T : M=4096, N=2048, K=2048 -> 128 blocks
  gemm8p<false><<<(B_ * L_ / 256) * (D_ / 256), 512, 0, stream>>>(
      Yb, wob, out, B_ * L_, D_, D_);
}

// Round 7
// 290.570 us; speedup vs baseline: 1.0515x; 1.0515x over previous
//
#include <hip/hip_runtime.h>
#include <math.h>

typedef __bf16 bf16x8 __attribute__((ext_vector_type(8)));
typedef float f32x4 __attribute__((ext_vector_type(4)));
typedef unsigned short us8 __attribute__((ext_vector_type(8)));

#define B_ 2
#define L_ 2048
#define D_ 2048
#define H_ 16
#define DH 128

__device__ __forceinline__ unsigned short f2b(float f) {
  union { float f; unsigned u; } v; v.f = f;
  unsigned u = v.u;
  return (unsigned short)((u + 0x7fffu + ((u >> 16) & 1u)) >> 16);
}
__device__ __forceinline__ float b2f(unsigned short h) {
  union { unsigned u; float f; } v; v.u = ((unsigned)h) << 16;
  return v.f;
}

#define GLD16(g, l) __builtin_amdgcn_global_load_lds(                          \
    (const __attribute__((address_space(1))) void*)(g),                        \
    (__attribute__((address_space(3))) void*)(l), 16, 0, 0)

#define SBAR() __builtin_amdgcn_s_barrier()
#define LGK0() asm volatile("s_waitcnt lgkmcnt(0)")
#define VMC6() asm volatile("s_waitcnt vmcnt(6)" ::: "memory")
#define VMC0() asm volatile("s_waitcnt vmcnt(0)" ::: "memory")

// ---------------- fp32 -> bf16 convert ----------------
__global__ void f32_to_bf16(const float* __restrict__ in,
                            unsigned short* __restrict__ out, int n4) {
  int i = blockIdx.x * blockDim.x + threadIdx.x;
  const int stride = gridDim.x * blockDim.x;
  for (; i < n4; i += stride) {
    const float4 v = ((const float4*)in)[i];
    ushort4 o;
    o.x = f2b(v.x); o.y = f2b(v.y); o.z = f2b(v.z); o.w = f2b(v.w);
    ((ushort4*)out)[i] = o;
  }
}

// ---------------- 128x256x64 GEMM, triple-buffered: C[m,n]=sum_k A[m,k]*B[n,k] ----
// 8 waves (2M x 4N), per-wave 64x64 C. 3 LDS buffers (144 KB): tile t stages
// tile t+2 (3 units/phase), vmcnt(6) at tile boundary drains only loads that
// are 2-3 phases old. 2 phases/tile (16-MFMA clusters by k-slice), 3 barriers
// per tile. T2 swizzle slot^(row&7) (row=128B = bank wrap -> conflict-free).
// Grids: GEMM1 768 = 3 exact CU-rounds, GEMM2 256 = 1 round; both %8==0.
template <bool OUT_BF16>
__global__ __launch_bounds__(512)
void gemm3b(const unsigned short* __restrict__ A,
            const unsigned short* __restrict__ Bm,
            void* __restrict__ Cv, int M, int N, int K) {
  __shared__ __align__(16) unsigned short lA[3][128 * 64];
  __shared__ __align__(16) unsigned short lB[3][2][128 * 64];
  const int tid = threadIdx.x;
  const int w = tid >> 6, lane = tid & 63;
  const int lo = lane & 15, hi = lane >> 4;
  const int mh = w >> 2;            // A half: rows [mh*64, mh*64+64)
  const int wn = (w & 3) * 64;      // C col window
  const int bhalf = wn >> 7;        // which 128-row half of B-tile
  const int brb = (wn & 64) + lo;   // row base within that half
  const int GM = M >> 7;
  const int nwg = gridDim.x;
  const int f = blockIdx.x;
  const int v = (f & 7) * (nwg >> 3) + (f >> 3);  // bijective XCD swizzle
  const int bn = v / GM, bm = v % GM;
  const int NT = K >> 6;

  const int row64 = tid >> 3;                 // staging row within 64-row unit
  const int gs = (tid & 7) ^ (row64 & 7);     // pre-swizzled source slot
  auto stA = [&](int buf, int u, int tile) {
    GLD16(A + (long)(bm * 128 + u * 64 + row64) * K + tile * 64 + gs * 8,
          &lA[buf][u * 4096 + (tid & ~63) * 8]);
  };
  auto stB = [&](int buf, int hf, int u, int tile) {
    GLD16(Bm + (long)(bn * 256 + hf * 128 + u * 64 + row64) * K + tile * 64 + gs * 8,
          &lB[buf][hf][u * 4096 + (tid & ~63) * 8]);
  };

  f32x4 acc[4][4] = {};

  // prologue: stage tile0 (6 units) + tile1 (6 units); wait for tile0
  stA(0, 0, 0); stA(0, 1, 0);
  stB(0, 0, 0, 0); stB(0, 0, 1, 0); stB(0, 1, 0, 0); stB(0, 1, 1, 0);
  stA(1, 0, 1); stA(1, 1, 1);
  stB(1, 0, 0, 1); stB(1, 0, 1, 1); stB(1, 1, 0, 1); stB(1, 1, 1, 1);
  VMC6();
  SBAR();

  for (int t = 0; t < NT; ++t) {
    const int bt = t % 3;
    const int b2 = (t + 2) % 3;
    const bool nx = (t + 2 < NT);
    bf16x8 af[4], bf[4];
    // ---- phase A: k-slice 0 ----
#pragma unroll
    for (int mi = 0; mi < 4; ++mi) {
      const int r = mh * 64 + mi * 16 + lo;
      af[mi] = *(const bf16x8*)&lA[bt][r * 64 + ((hi ^ (r & 7)) * 8)];
    }
#pragma unroll
    for (int ni = 0; ni < 4; ++ni) {
      const int rb = brb + ni * 16;
      bf[ni] = *(const bf16x8*)&lB[bt][bhalf][rb * 64 + ((hi ^ (rb & 7)) * 8)];
    }
    if (nx) { stA(b2, 0, t + 2); stA(b2, 1, t + 2); stB(b2, 0, 0, t + 2); }
    SBAR(); LGK0();
    __builtin_amdgcn_s_setprio(1);
#pragma unroll
    for (int mi = 0; mi < 4; ++mi)
#pragma unroll
      for (int ni = 0; ni < 4; ++ni)
        acc[mi][ni] = __builtin_amdgcn_mfma_f32_16x16x32_bf16(
            af[mi], bf[ni], acc[mi][ni], 0, 0, 0);
    __builtin_amdgcn_s_setprio(0);
    // ---- phase B: k-slice 1 (same buffer; no barrier needed before reads) ----
#pragma unroll
    for (int mi = 0; mi < 4; ++mi) {
      const int r = mh * 64 + mi * 16 + lo;
      af[mi] = *(const bf16x8*)&lA[bt][r * 64 + (((4 + hi) ^ (r & 7)) * 8)];
    }
#pragma unroll
    for (int ni = 0; ni < 4; ++ni) {
      const int rb = brb + ni * 16;
      bf[ni] = *(const bf16x8*)&lB[bt][bhalf][rb * 64 + (((4 + hi) ^ (rb & 7)) * 8)];
    }
    if (nx) { stB(b2, 0, 1, t + 2); stB(b2, 1, 0, t + 2); stB(b2, 1, 1, t + 2); }
    SBAR(); LGK0();
    __builtin_amdgcn_s_setprio(1);
#pragma unroll
    for (int mi = 0; mi < 4; ++mi)
#pragma unroll
      for (int ni = 0; ni < 4; ++ni)
        acc[mi][ni] = __builtin_amdgcn_mfma_f32_16x16x32_bf16(
            af[mi], bf[ni], acc[mi][ni], 0, 0, 0);
    __builtin_amdgcn_s_setprio(0);
    if (t < NT - 2) VMC6(); else VMC0();  // next tile's 6 units landed
    SBAR();
  }

  const int r0 = bm * 128 + mh * 64;
  const int c0 = bn * 256 + wn;
#pragma unroll
  for (int mi = 0; mi < 4; ++mi) {
#pragma unroll
    for (int r = 0; r < 4; ++r) {
      const long row = r0 + mi * 16 + hi * 4 + r;
#pragma unroll
      for (int ni = 0; ni < 4; ++ni) {
        const int col = c0 + ni * 16 + lo;
        if (OUT_BF16)
          ((unsigned short*)Cv)[row * N + col] = f2b(acc[mi][ni][r]);
        else
          ((float*)Cv)[row * N + col] = acc[mi][ni][r];
      }
    }
  }
}

// ---------------- RoPE + scatter to [B,H,L,dh]; Q scaled by log2(e)/sqrt(dh) ----------------
__global__ void rope_qk(const unsigned short* __restrict__ qkv,
                        unsigned short* __restrict__ Qo,
                        unsigned short* __restrict__ Ko) {
  const int idx = blockIdx.x * 256 + threadIdx.x;
  const int i = idx & 63;
  const int l = (idx >> 6) & (L_ - 1);
  const int h = (idx >> 17) & (H_ - 1);
  const int b = idx >> 21;
  const float invf = exp2f(-(float)i * 0.20762050593045077f);
  const float ang = (float)l * invf;
  float sn, cs;
  sincosf(ang, &sn, &cs);
  const long base = ((long)b * L_ + l) * (3 * D_) + h * DH + 2 * i;
  const unsigned qin = *(const unsigned*)&qkv[base];
  const unsigned kin = *(const unsigned*)&qkv[base + D_];
  const float q0 = b2f((unsigned short)qin), q1 = b2f((unsigned short)(qin >> 16));
  const float k0 = b2f((unsigned short)kin), k1 = b2f((unsigned short)(kin >> 16));
  const float sc = 0.12751743f;  // log2(e)/sqrt(128): softmax in exp2 domain
  const float qo0 = (q0 * cs - q1 * sn) * sc, qo1 = (q1 * cs + q0 * sn) * sc;
  const float ko0 = (k0 * cs - k1 * sn), ko1 = (k1 * cs + k0 * sn);
  const long oo = ((long)(b * H_ + h) * L_ + l) * DH + 2 * i;
  *(unsigned*)&Qo[oo] = (unsigned)f2b(qo0) | ((unsigned)f2b(qo1) << 16);
  *(unsigned*)&Ko[oo] = (unsigned)f2b(ko0) | ((unsigned)f2b(ko1) << 16);
}

// ---------------- V pack into MFMA B-fragment tiles ----------------
__global__ __launch_bounds__(256)
void v_fragpack(const unsigned short* __restrict__ qkv,
                unsigned short* __restrict__ Vf) {
  const int lblk = blockIdx.x;  // L/64
  const int bh = blockIdx.y;    // B*H
  const int b = bh >> 4, h = bh & 15;
  __shared__ unsigned short tile[64 * 137];
  const int tid = threadIdx.x;
  const int l0 = lblk * 64;
#pragma unroll
  for (int j = 0; j < 4; ++j) {
    const int c = j * 256 + tid;
    const int row = c >> 4, col8 = c & 15;
    const us8 v = *(const us8*)&qkv[((long)b * L_ + l0 + row) * (3 * D_) +
                                    2 * D_ + h * DH + col8 * 8];
    unsigned short* dst = &tile[row * 137 + col8 * 8];
#pragma unroll
    for (int e = 0; e < 8; ++e) dst[e] = v[e];
  }
  __syncthreads();
#pragma unroll
  for (int j = 0; j < 4; ++j) {
    const int c = j * 256 + tid;
    const int k32l = c >> 9, t2 = (c >> 6) & 7, lane = c & 63;
    const int lo = lane & 15, hi = lane >> 4;
    us8 v;
#pragma unroll
    for (int e = 0; e < 8; ++e)
      v[e] = tile[(k32l * 32 + hi * 8 + e) * 137 + t2 * 16 + lo];
    *(us8*)&Vf[(((size_t)bh * 64 + lblk * 2 + k32l) * 8 + t2) * 512 + lane * 8] = v;
  }
}

// ---------------- causal flash attention: fold-paired q-tiles, swapped QK^T ----------------
__global__ __launch_bounds__(256, 2)
void flash_attn3(const unsigned short* __restrict__ Q,
                 const unsigned short* __restrict__ Kg,
                 const unsigned short* __restrict__ Vf,
                 unsigned short* __restrict__ Y) {
  const int p = blockIdx.x;  // 0..15
  const int tA = p, tB = (L_ / 64 - 1) - p;
  const int h = blockIdx.y, b = blockIdx.z;
  const int tid = threadIdx.x;
  const int wave = tid >> 6, lane = tid & 63;
  const int lo = lane & 15, hi = lane >> 4;
  const int swz = (lo & 7) << 4;
  const int qA = tA * 64 + wave * 16;
  const int qB = tB * 64 + wave * 16;
  const long hoff = ((long)(b * H_ + h)) * L_ * DH;
  const unsigned short* Qh = Q + hoff;
  const unsigned short* Kh = Kg + hoff;
  const unsigned short* Vfh = Vf + ((size_t)(b * H_ + h)) * (64 * 8 * 512);

  __shared__ unsigned short lK[2][64 * 128];
  __shared__ unsigned short pl[4][2][16 * 72];
  unsigned short* plA = &pl[wave][0][0];
  unsigned short* plB = &pl[wave][1][0];

  auto stage = [&](int bufi, int kv0s) {
    unsigned short* bk = &lK[bufi][0];
#pragma unroll
    for (int j = 0; j < 4; ++j) {
      const int c = j * 256 + tid;
      const int row = c >> 4;
      const int soff = ((c & 15) ^ (row & 7)) << 3;
      GLD16(Kh + (long)(kv0s + row) * DH + soff, &bk[(c & ~63) * 8]);
    }
  };

  bf16x8 qfA[4], qfB[4];
#pragma unroll
  for (int s = 0; s < 4; ++s) {
    qfA[s] = *(const bf16x8*)&Qh[(long)(qA + lo) * DH + s * 32 + hi * 8];
    qfB[s] = *(const bf16x8*)&Qh[(long)(qB + lo) * DH + s * 32 + hi * 8];
  }

  float mA = -INFINITY, lsA = 0.f, mB = -INFINITY, lsB = 0.f;
  f32x4 yA[8] = {}, yB[8] = {};

  auto softmax = [&](f32x4 (&st)[4], float& m, float& lsum, f32x4 (&yacc)[8],
                     unsigned short* plw, int qw, int kv0) {
    if (kv0 + 63 > qw) {
      const int d0 = qw + lo - kv0 - hi * 4;
#pragma unroll
      for (int t = 0; t < 4; ++t) {
        const int dt = d0 - t * 16;
#pragma unroll
        for (int r = 0; r < 4; ++r)
          if (r > dt) st[t][r] = -INFINITY;
      }
    }
    float tm0 = fmaxf(fmaxf(st[0][0], st[0][1]), fmaxf(st[0][2], st[0][3]));
    float tm1 = fmaxf(fmaxf(st[1][0], st[1][1]), fmaxf(st[1][2], st[1][3]));
    float tm2 = fmaxf(fmaxf(st[2][0], st[2][1]), fmaxf(st[2][2], st[2][3]));
    float tm3 = fmaxf(fmaxf(st[3][0], st[3][1]), fmaxf(st[3][2], st[3][3]));
    float rm = fmaxf(fmaxf(tm0, tm1), fmaxf(tm2, tm3));
    rm = fmaxf(rm, __shfl_xor(rm, 16));
    rm = fmaxf(rm, __shfl_xor(rm, 32));
    if (!__all(rm <= m + 8.f)) {
      const float mn = fmaxf(m, rm);
      const float alpha = exp2f(m - mn);
      m = mn;
      lsum *= alpha;
      float ar[4];
#pragma unroll
      for (int r = 0; r < 4; ++r) ar[r] = __shfl(alpha, hi * 4 + r);
#pragma unroll
      for (int t2 = 0; t2 < 8; ++t2)
#pragma unroll
        for (int r = 0; r < 4; ++r) yacc[t2][r] *= ar[r];
    }
    float rs = 0.f;
#pragma unroll
    for (int t = 0; t < 4; ++t) {
#pragma unroll
      for (int r2 = 0; r2 < 2; ++r2) {
        const float e0 = exp2f(st[t][2 * r2] - m);
        const float e1 = exp2f(st[t][2 * r2 + 1] - m);
        rs += e0 + e1;
        const unsigned short u0 = __builtin_bit_cast(unsigned short, (__bf16)e0);
        const unsigned short u1 = __builtin_bit_cast(unsigned short, (__bf16)e1);
        *(unsigned*)&plw[lo * 72 + t * 16 + hi * 4 + 2 * r2] =
            (unsigned)u0 | ((unsigned)u1 << 16);
      }
    }
    rs += __shfl_xor(rs, 16);
    rs += __shfl_xor(rs, 32);
    lsum += rs;
  };

  const int nIter = tB + 1;
  stage(0, 0);
  __syncthreads();

  for (int it = 0; it < nIter; ++it) {
    const int kv0 = it * 64;
    const bool aAct = (it <= tA);
    if (it + 1 < nIter) stage((it + 1) & 1, kv0 + 64);
    const char* bkc = (const char*)&lK[it & 1][0];
    f32x4 stA[4] = {}, stB[4] = {};
    if (aAct) {
#pragma unroll
      for (int s = 0; s < 4; ++s) {
        const int inner = (lo * 256 + s * 64 + hi * 16) ^ swz;
#pragma unroll
        for (int t = 0; t < 4; ++t) {
          const bf16x8 kf = *(const bf16x8*)(bkc + t * 4096 + inner);
          stA[t] = __builtin_amdgcn_mfma_f32_16x16x32_bf16(kf, qfA[s], stA[t], 0, 0, 0);
          stB[t] = __builtin_amdgcn_mfma_f32_16x16x32_bf16(kf, qfB[s], stB[t], 0, 0, 0);
        }
      }
    } else {
#pragma unroll
      for (int s = 0; s < 4; ++s) {
        const int inner = (lo * 256 + s * 64 + hi * 16) ^ swz;
#pragma unroll
        for (int t = 0; t < 4; ++t) {
          const bf16x8 kf = *(const bf16x8*)(bkc + t * 4096 + inner);
          stB[t] = __builtin_amdgcn_mfma_f32_16x16x32_bf16(kf, qfB[s], stB[t], 0, 0, 0);
        }
      }
    }
    if (aAct) softmax(stA, mA, lsA, yA, plA, qA, kv0);
    softmax(stB, mB, lsB, yB, plB, qB, kv0);
    const unsigned short* vbase = Vfh + (size_t)(it * 16) * 512 + lane * 8;
#pragma unroll
    for (int kt = 0; kt < 2; ++kt) {
      bf16x8 vf[8];
#pragma unroll
      for (int t2 = 0; t2 < 8; ++t2)
        vf[t2] = *(const bf16x8*)(vbase + (size_t)(kt * 8 + t2) * 512);
      const bf16x8 pfB = *(const bf16x8*)&plB[lo * 72 + kt * 32 + hi * 8];
#pragma unroll
      for (int t2 = 0; t2 < 8; ++t2)
        yB[t2] = __builtin_amdgcn_mfma_f32_16x16x32_bf16(pfB, vf[t2], yB[t2], 0, 0, 0);
      if (aAct) {
        const bf16x8 pfA = *(const bf16x8*)&plA[lo * 72 + kt * 32 + hi * 8];
#pragma unroll
        for (int t2 = 0; t2 < 8; ++t2)
          yA[t2] = __builtin_amdgcn_mfma_f32_16x16x32_bf16(pfA, vf[t2], yA[t2], 0, 0, 0);
      }
    }
    __syncthreads();
  }

  auto wout = [&](f32x4 (&yacc)[8], float lsum, int qw) {
    const float inv = 1.f / lsum;
    float ir[4];
#pragma unroll
    for (int r = 0; r < 4; ++r) ir[r] = __shfl(inv, hi * 4 + r);
#pragma unroll
    for (int r = 0; r < 4; ++r) {
      const long row = qw + hi * 4 + r;
      unsigned short* yrow = Y + ((long)b * L_ + row) * D_ + h * DH;
#pragma unroll
      for (int t2 = 0; t2 < 8; ++t2)
        yrow[t2 * 16 + lo] = f2b(yacc[t2][r] * ir[r]);
    }
  };
  wout(yA, lsA, qA);
  wout(yB, lsB, qB);
}

extern "C" void kernel_launch(void* const* d_in, const int* in_sizes, int n_in,
                              void* d_out, int out_size, void* d_ws, size_t ws_size,
                              hipStream_t stream) {
  const float* x = (const float*)d_in[0];
  const float* wqkv = (const float*)d_in[1];
  const float* wo = (const float*)d_in[2];
  float* out = (float*)d_out;

  unsigned short* ws = (unsigned short*)d_ws;
  const size_t N_X = (size_t)B_ * L_ * D_;
  const size_t N_WQKV = (size_t)3 * D_ * D_;
  const size_t N_WO = (size_t)D_ * D_;
  const size_t N_QKV = (size_t)B_ * L_ * 3 * D_;
  const size_t N_HEAD = (size_t)B_ * H_ * L_ * DH;
  unsigned short* xb = ws;
  unsigned short* wqkb = xb + N_X;
  unsigned short* wob = wqkb + N_WQKV;
  unsigned short* qkv = wob + N_WO;
  unsigned short* Qb = qkv + N_QKV;
  unsigned short* Kb = Qb + N_HEAD;
  unsigned short* Vf = Kb + N_HEAD;
  unsigned short* Yb = Vf + N_HEAD;
  const size_t need = (size_t)(Yb + N_HEAD - ws) * sizeof(unsigned short);
  if (ws_size < need) return;

  f32_to_bf16<<<2048, 256, 0, stream>>>(x, xb, (int)(N_X / 4));
  f32_to_bf16<<<2048, 256, 0, stream>>>(wqkv, wqkb, (int)(N_WQKV / 4));
  f32_to_bf16<<<2048, 256, 0, stream>>>(wo, wob, (int)(N_WO / 4));

  // qkv = x @ W_qkv^T : M=4096, N=6144, K=2048 -> 32x24 = 768 blocks (3 rounds)
  gemm3b<true><<<(B_ * L_ / 128) * (3 * D_ / 256), 512, 0, stream>>>(
      xb, wqkb, qkv, B_ * L_, 3 * D_, D_);

  rope_qk<<<(B_ * H_ * L_ * 64) / 256, 256, 0, stream>>>(qkv, Qb, Kb);
  v_fragpack<<<dim3(L_ / 64, B_ * H_), 256, 0, stream>>>(qkv, Vf);

  flash_attn3<<<dim3(16, H_, B_), 256, 0, stream>>>(Qb, Kb, Vf, Yb);

  // out = y @ W_o^T : M=4096, N=2048, K=2048 -> 32x8 = 256 blocks (1 round)
  gemm3b<false><<<(B_ * L_ / 128) * (D_ / 256), 512, 0, stream>>>(
      Yb, wob, out, B_ * L_, D_, D_);
}